// Round 13
// baseline (214.432 us; speedup 1.0000x reference)
//
#include <hip/hip_runtime.h>

#define N_NODES 100000
#define N_EDGES 50000
#define NNZ     800000
#define D       256

#define BM 64            // gemm rows per block
#define GEMM_BLOCKS ((N_NODES + BM - 1) / BM)   // 1563

// bucket-sort CSR build (fixed-base gapped buckets, CAP >> max count)
#define NB   98          // buckets per direction
#define ESH  9           // edge bucket shift: 512 keys/bucket
#define VSH  10          // node bucket shift: 1024 keys/bucket
#define CAP  16384       // per-bucket capacity (mean ~8.2k, 5-sigma ~8.7k)
#define ENT  4096        // entries per multisplit block
#define MS_BLOCKS ((NNZ + ENT - 1) / ENT)   // 196

#define EG_BLOCKS ((N_EDGES * 64) / 256)    // 12500 edge-gather blocks

typedef __bf16 bf16x8 __attribute__((ext_vector_type(8)));
typedef float  f32x4  __attribute__((ext_vector_type(4)));
typedef unsigned int u32x4 __attribute__((ext_vector_type(4)));

// accumulate 8 bf16 (packed in u32x4) into 8 f32 accumulators
__device__ __forceinline__ void acc8(float* a, const u32x4 u) {
    union { unsigned int i; float f; } t;
    t.i = u.x << 16;         a[0] += t.f;
    t.i = u.x & 0xffff0000u; a[1] += t.f;
    t.i = u.y << 16;         a[2] += t.f;
    t.i = u.y & 0xffff0000u; a[3] += t.f;
    t.i = u.z << 16;         a[4] += t.f;
    t.i = u.z & 0xffff0000u; a[5] += t.f;
    t.i = u.w << 16;         a[6] += t.f;
    t.i = u.w & 0xffff0000u; a[7] += t.f;
}

__device__ __forceinline__ void unpack8(float* a, const u32x4 u) {
    union { unsigned int i; float f; } t;
    t.i = u.x << 16;         a[0] = t.f;
    t.i = u.x & 0xffff0000u; a[1] = t.f;
    t.i = u.y << 16;         a[2] = t.f;
    t.i = u.y & 0xffff0000u; a[3] = t.f;
    t.i = u.z << 16;         a[4] = t.f;
    t.i = u.z & 0xffff0000u; a[5] = t.f;
    t.i = u.w << 16;         a[6] = t.f;
    t.i = u.w & 0xffff0000u; a[7] = t.f;
}

// ---------------------------------------------------------------------------
// Shared CSR-build body (one bucket, one direction). Folded bucket scan:
// re-derive the 98-bucket exclusive prefix from counts, then per-key count +
// LDS scan -> CSR offsets, then rank gapped tmp entries into packed src.
// ---------------------------------------------------------------------------
__device__ __forceinline__ void build_dir(const unsigned int* __restrict__ tmp,
                                          const int* __restrict__ gc,
                                          int* __restrict__ off,
                                          int* __restrict__ src,
                                          const int b, const int sh,
                                          const int ksh, const int nkeys) {
    __shared__ int cnt[1024];
    __shared__ int s[256];
    const unsigned pmask = (1u << ksh) - 1u;
    const int klo = b << sh;
    const int nk  = min(1 << sh, nkeys - klo);
    const int t = threadIdx.x;

    int c = (t < NB) ? gc[t] : 0;
    s[t] = c; __syncthreads();
    #pragma unroll
    for (int d = 1; d < 256; d <<= 1) { int x = (t >= d) ? s[t - d] : 0; __syncthreads(); s[t] += x; __syncthreads(); }
    const int base_out = s[b] - gc[b];
    const int count    = gc[b];
    const int base_in  = b * CAP;
    __syncthreads();

    if (t == 0 && b == 0) off[nkeys] = NNZ;

    #pragma unroll
    for (int q = 0; q < 4; ++q) cnt[t * 4 + q] = 0;
    __syncthreads();
    for (int i = t; i < count; i += 256)
        atomicAdd(&cnt[tmp[base_in + i] >> ksh], 1);
    __syncthreads();
    int v[4]; int ts = 0;
    #pragma unroll
    for (int q = 0; q < 4; ++q) { v[q] = cnt[t * 4 + q]; ts += v[q]; }
    s[t] = ts; __syncthreads();
    #pragma unroll
    for (int d = 1; d < 256; d <<= 1) { int x = (t >= d) ? s[t - d] : 0; __syncthreads(); s[t] += x; __syncthreads(); }
    int run = s[t] - ts;
    #pragma unroll
    for (int q = 0; q < 4; ++q) { cnt[t * 4 + q] = run; run += v[q]; }
    __syncthreads();
    #pragma unroll
    for (int q = 0; q < 4; ++q) {
        const int j = t * 4 + q;
        if (j < nk) off[klo + j] = base_out + cnt[j];
    }
    __syncthreads();
    for (int i = t; i < count; i += 256) {
        const unsigned int pr = tmp[base_in + i];
        const int p = atomicAdd(&cnt[pr >> ksh], 1);
        src[base_out + p] = (int)(pr & pmask);
    }
}

// ---------------------------------------------------------------------------
// Kernel 0: pack W (f32 [256][256]) into bf16 MFMA b-fragment order.
// ---------------------------------------------------------------------------
__global__ __launch_bounds__(256) void pack_W(const float* __restrict__ W,
                                              bf16x8* __restrict__ Wp) {
    const int t = blockIdx.x * 256 + threadIdx.x;   // 8192 total
    if (t >= 8 * 16 * 64) return;
    const int ks  = t >> 10;
    const int n16 = (t >> 6) & 15;
    const int l   = t & 63;
    const int kb  = ks * 32 + (l >> 4) * 8;
    const int col = n16 * 16 + (l & 15);
    bf16x8 v;
    #pragma unroll
    for (int j = 0; j < 8; ++j) v[j] = (__bf16)W[(size_t)(kb + j) * D + col];
    Wp[t] = v;
}

// ---------------------------------------------------------------------------
// Fused kernel 1: blocks [0, MS_BLOCKS) = multisplit, rest = MFMA GEMM.
// ---------------------------------------------------------------------------
__global__ __launch_bounds__(256) void gemm_multisplit_fused(
        const float* __restrict__ X, const bf16x8* __restrict__ Wp,
        __bf16* __restrict__ Xpb,
        const int* __restrict__ ei, const int* __restrict__ ni,
        int* __restrict__ ecnt, int* __restrict__ vcnt,
        unsigned int* __restrict__ etmp, unsigned int* __restrict__ vtmp) {
    __shared__ __align__(16) char smem[BM * D * sizeof(__bf16)];  // 32 KB
    const int tid = threadIdx.x;

    if (blockIdx.x < MS_BLOCKS) {
        int* eh = reinterpret_cast<int*>(smem);
        int* vh = eh + 128;
        int* eb = vh + 128;
        int* vb = eb + 128;
        if (tid < 128) { eh[tid] = 0; vh[tid] = 0; }
        __syncthreads();
        const int start = blockIdx.x * ENT;
        int ek[ENT / 256], nk[ENT / 256];
        #pragma unroll
        for (int k = 0; k < ENT / 256; ++k) {
            const int g = start + k * 256 + tid;
            if (g < NNZ) {
                ek[k] = __builtin_nontemporal_load(ei + g);
                nk[k] = __builtin_nontemporal_load(ni + g);
                atomicAdd(&eh[ek[k] >> ESH], 1);
                atomicAdd(&vh[nk[k] >> VSH], 1);
            } else { ek[k] = -1; nk[k] = -1; }
        }
        __syncthreads();
        if (tid < NB) {
            eb[tid] = eh[tid] ? (tid * CAP + atomicAdd(&ecnt[tid], eh[tid])) : 0;
            vb[tid] = vh[tid] ? (tid * CAP + atomicAdd(&vcnt[tid], vh[tid])) : 0;
        }
        __syncthreads();
        if (tid < 128) { eh[tid] = 0; vh[tid] = 0; }
        __syncthreads();
        #pragma unroll
        for (int k = 0; k < ENT / 256; ++k) {
            if (ek[k] >= 0) {
                int b = ek[k] >> ESH;
                int r = atomicAdd(&eh[b], 1);
                etmp[eb[b] + r] = ((unsigned)(ek[k] & ((1 << ESH) - 1)) << 17) | (unsigned)nk[k];
                b = nk[k] >> VSH;
                r = atomicAdd(&vh[b], 1);
                vtmp[vb[b] + r] = ((unsigned)(nk[k] & ((1 << VSH) - 1)) << 16) | (unsigned)ek[k];
            }
        }
        return;
    }

    // ================= GEMM =================
    __bf16 (*As)[D] = reinterpret_cast<__bf16 (*)[D]>(smem);
    const int r0 = (blockIdx.x - MS_BLOCKS) * BM;

    #pragma unroll
    for (int i = 0; i < 8; ++i) {
        const int g   = tid + i * 256;
        const int row = g >> 5;
        const int cc  = g & 31;
        const int gr  = min(r0 + row, N_NODES - 1);
        const float4 f0 = reinterpret_cast<const float4*>(X)[(size_t)gr * 64 + cc * 2 + 0];
        const float4 f1 = reinterpret_cast<const float4*>(X)[(size_t)gr * 64 + cc * 2 + 1];
        bf16x8 v;
        v[0] = (__bf16)f0.x; v[1] = (__bf16)f0.y; v[2] = (__bf16)f0.z; v[3] = (__bf16)f0.w;
        v[4] = (__bf16)f1.x; v[5] = (__bf16)f1.y; v[6] = (__bf16)f1.z; v[7] = (__bf16)f1.w;
        const int sw = cc ^ (row & 7);
        *reinterpret_cast<bf16x8*>(&As[row][sw * 8]) = v;
    }
    __syncthreads();

    const int w = tid >> 6;
    const int l = tid & 63;

    f32x4 acc[4][4];
    #pragma unroll
    for (int mt = 0; mt < 4; ++mt)
        #pragma unroll
        for (int nt = 0; nt < 4; ++nt) acc[mt][nt] = (f32x4){0.f, 0.f, 0.f, 0.f};

    #pragma unroll
    for (int ks = 0; ks < 8; ++ks) {
        bf16x8 a[4];
        #pragma unroll
        for (int mt = 0; mt < 4; ++mt) {
            const int row = mt * 16 + (l & 15);
            const int ch  = (ks * 4 + (l >> 4)) ^ (row & 7);
            a[mt] = *reinterpret_cast<const bf16x8*>(&As[row][ch * 8]);
        }
        #pragma unroll
        for (int nt = 0; nt < 4; ++nt) {
            const bf16x8 b = Wp[(ks * 16 + w * 4 + nt) * 64 + l];
            #pragma unroll
            for (int mt = 0; mt < 4; ++mt)
                acc[mt][nt] = __builtin_amdgcn_mfma_f32_16x16x32_bf16(a[mt], b, acc[mt][nt], 0, 0, 0);
        }
    }

    #pragma unroll
    for (int mt = 0; mt < 4; ++mt) {
        const int rbase = r0 + mt * 16 + (l >> 4) * 4;
        #pragma unroll
        for (int reg = 0; reg < 4; ++reg) {
            const int r = rbase + reg;
            if (r >= N_NODES) continue;
            #pragma unroll
            for (int nt = 0; nt < 4; ++nt)
                Xpb[(size_t)r * D + w * 64 + nt * 16 + (l & 15)] = (__bf16)acc[mt][nt][reg];
        }
    }
}

// ---------------------------------------------------------------------------
// Kernel 2: edge-direction CSR pack only (critical path for edge_gather).
// ---------------------------------------------------------------------------
__global__ __launch_bounds__(256) void build_csr_edge(
        const unsigned int* __restrict__ etmp, const int* __restrict__ ecnt,
        int* __restrict__ eoff, int* __restrict__ esrc) {
    build_dir(etmp, ecnt, eoff, esrc, blockIdx.x, ESH, 17, N_EDGES);
}

// ---------------------------------------------------------------------------
// Fused kernel 3: blocks [0, NB) = node-direction CSR pack (hidden under the
// gather); blocks [NB, NB+EG_BLOCKS) = edge gather.
//   Xe[e] = degE[e] * sum_{j in edge e} Xp[esrc[j]]
// ---------------------------------------------------------------------------
__global__ __launch_bounds__(256) void edge_gather_fused(
        const __bf16* __restrict__ Xpb, const int* __restrict__ eoff,
        const int* __restrict__ esrc, const float* __restrict__ degE,
        __bf16* __restrict__ Xeb,
        const unsigned int* __restrict__ vtmp, const int* __restrict__ vcnt,
        int* __restrict__ voff, int* __restrict__ vsrc) {
    if (blockIdx.x < NB) {
        build_dir(vtmp, vcnt, voff, vsrc, blockIdx.x, VSH, 16, N_NODES);
        return;
    }
    const int e = ((blockIdx.x - NB) * 256 + threadIdx.x) >> 6;
    if (e >= N_EDGES) return;
    const int lane = threadIdx.x & 63;
    const int half = lane >> 5;
    const int c0   = (lane & 31) * 8;
    const int beg = eoff[e], end = eoff[e + 1];
    const unsigned short* Xu = reinterpret_cast<const unsigned short*>(Xpb);

    float acc[8];
    #pragma unroll
    for (int q = 0; q < 8; ++q) acc[q] = 0.f;

    for (int cb = beg; cb < end; cb += 64) {
        const int cnt = min(64, end - cb);
        const int my = (lane < cnt) ? __builtin_nontemporal_load(esrc + cb + lane) : 0;
        int jj = 0;
        for (; jj + 8 <= cnt; jj += 8) {
            const int r0 = __shfl(my, jj + half);
            const int r1 = __shfl(my, jj + 2 + half);
            const int r2 = __shfl(my, jj + 4 + half);
            const int r3 = __shfl(my, jj + 6 + half);
            const u32x4 u0 = *reinterpret_cast<const u32x4*>(Xu + (size_t)r0 * D + c0);
            const u32x4 u1 = *reinterpret_cast<const u32x4*>(Xu + (size_t)r1 * D + c0);
            const u32x4 u2 = *reinterpret_cast<const u32x4*>(Xu + (size_t)r2 * D + c0);
            const u32x4 u3 = *reinterpret_cast<const u32x4*>(Xu + (size_t)r3 * D + c0);
            acc8(acc, u0); acc8(acc, u1); acc8(acc, u2); acc8(acc, u3);
        }
        for (; jj + 4 <= cnt; jj += 4) {
            const int r0 = __shfl(my, jj + half);
            const int r1 = __shfl(my, jj + 2 + half);
            const u32x4 u0 = *reinterpret_cast<const u32x4*>(Xu + (size_t)r0 * D + c0);
            const u32x4 u1 = *reinterpret_cast<const u32x4*>(Xu + (size_t)r1 * D + c0);
            acc8(acc, u0); acc8(acc, u1);
        }
        for (; jj < cnt; jj += 2) {
            const int rr = jj + half;
            const int r = __shfl(my, rr < cnt ? rr : cnt - 1);
            if (rr < cnt) {
                const u32x4 u = *reinterpret_cast<const u32x4*>(Xu + (size_t)r * D + c0);
                acc8(acc, u);
            }
        }
    }

    #pragma unroll
    for (int q = 0; q < 8; ++q) acc[q] += __shfl_xor(acc[q], 32);

    if (half == 0) {
        const float sc = degE[e];
        bf16x8 v;
        #pragma unroll
        for (int q = 0; q < 8; ++q) v[q] = (__bf16)(acc[q] * sc);
        __builtin_nontemporal_store(v, reinterpret_cast<bf16x8*>(
            Xeb + (size_t)e * D + c0));
    }
}

// ---------------------------------------------------------------------------
// Kernel 4 (fused finalize):
//   out[n] = (1+eps)*Xp[n] + degV[n] * sum_{j in node n} Xe[vsrc[j]]
// ---------------------------------------------------------------------------
__global__ __launch_bounds__(256) void node_gather(
        const __bf16* __restrict__ Xpb, const __bf16* __restrict__ Xeb,
        const int* __restrict__ voff, const int* __restrict__ vsrc,
        const float* __restrict__ degV, const float* __restrict__ eps,
        float* __restrict__ out) {
    const int nd = (blockIdx.x * 256 + threadIdx.x) >> 6;
    if (nd >= N_NODES) return;
    const int lane = threadIdx.x & 63;
    const int half = lane >> 5;
    const int c0   = (lane & 31) * 8;
    const int beg = voff[nd], end = voff[nd + 1];
    const unsigned short* Xu = reinterpret_cast<const unsigned short*>(Xeb);

    const u32x4 up = __builtin_nontemporal_load(reinterpret_cast<const u32x4*>(
        reinterpret_cast<const unsigned short*>(Xpb) + (size_t)nd * D + c0));

    float acc[8];
    #pragma unroll
    for (int q = 0; q < 8; ++q) acc[q] = 0.f;

    for (int cb = beg; cb < end; cb += 64) {
        const int cnt = min(64, end - cb);
        const int my = (lane < cnt) ? __builtin_nontemporal_load(vsrc + cb + lane) : 0;
        int jj = 0;
        for (; jj + 8 <= cnt; jj += 8) {
            const int r0 = __shfl(my, jj + half);
            const int r1 = __shfl(my, jj + 2 + half);
            const int r2 = __shfl(my, jj + 4 + half);
            const int r3 = __shfl(my, jj + 6 + half);
            const u32x4 u0 = *reinterpret_cast<const u32x4*>(Xu + (size_t)r0 * D + c0);
            const u32x4 u1 = *reinterpret_cast<const u32x4*>(Xu + (size_t)r1 * D + c0);
            const u32x4 u2 = *reinterpret_cast<const u32x4*>(Xu + (size_t)r2 * D + c0);
            const u32x4 u3 = *reinterpret_cast<const u32x4*>(Xu + (size_t)r3 * D + c0);
            acc8(acc, u0); acc8(acc, u1); acc8(acc, u2); acc8(acc, u3);
        }
        for (; jj + 4 <= cnt; jj += 4) {
            const int r0 = __shfl(my, jj + half);
            const int r1 = __shfl(my, jj + 2 + half);
            const u32x4 u0 = *reinterpret_cast<const u32x4*>(Xu + (size_t)r0 * D + c0);
            const u32x4 u1 = *reinterpret_cast<const u32x4*>(Xu + (size_t)r1 * D + c0);
            acc8(acc, u0); acc8(acc, u1);
        }
        for (; jj < cnt; jj += 2) {
            const int rr = jj + half;
            const int r = __shfl(my, rr < cnt ? rr : cnt - 1);
            if (rr < cnt) {
                const u32x4 u = *reinterpret_cast<const u32x4*>(Xu + (size_t)r * D + c0);
                acc8(acc, u);
            }
        }
    }

    #pragma unroll
    for (int q = 0; q < 8; ++q) acc[q] += __shfl_xor(acc[q], 32);

    if (half == 0) {
        const float dv = degV[nd];
        const float ep = 1.f + eps[0];
        float xr[8]; unpack8(xr, up);
        f32x4 o0, o1;
        o0.x = ep * xr[0] + dv * acc[0];
        o0.y = ep * xr[1] + dv * acc[1];
        o0.z = ep * xr[2] + dv * acc[2];
        o0.w = ep * xr[3] + dv * acc[3];
        o1.x = ep * xr[4] + dv * acc[4];
        o1.y = ep * xr[5] + dv * acc[5];
        o1.z = ep * xr[6] + dv * acc[6];
        o1.w = ep * xr[7] + dv * acc[7];
        float* op = out + (size_t)nd * D + c0;
        __builtin_nontemporal_store(o0, reinterpret_cast<f32x4*>(op));
        __builtin_nontemporal_store(o1, reinterpret_cast<f32x4*>(op) + 1);
    }
}

// ---------------------------------------------------------------------------
extern "C" void kernel_launch(void* const* d_in, const int* in_sizes, int n_in,
                              void* d_out, int out_size, void* d_ws, size_t ws_size,
                              hipStream_t stream) {
    const float* X        = (const float*)d_in[0];
    const float* W        = (const float*)d_in[1];
    const float* eps      = (const float*)d_in[2];
    const float* degE     = (const float*)d_in[3];
    const float* degV     = (const float*)d_in[4];
    const int*   node_idx = (const int*)d_in[5];
    const int*   edge_idx = (const int*)d_in[6];

    float* out = (float*)d_out;

    // ---- workspace layout ----
    char* p = (char*)d_ws;
    __bf16* Xpb = (__bf16*)p; p += (size_t)N_NODES * D * sizeof(__bf16);  // 51.2 MB
    __bf16* Xeb = (__bf16*)p; p += (size_t)N_EDGES * D * sizeof(__bf16);  // 25.6 MB
    bf16x8* Wp  = (bf16x8*)p; p += (size_t)8 * 16 * 64 * sizeof(bf16x8);  // 128 KB
    unsigned int* etmp = (unsigned int*)p; p += (size_t)NB * CAP * sizeof(unsigned int); // 6.4 MB
    unsigned int* vtmp = (unsigned int*)p; p += (size_t)NB * CAP * sizeof(unsigned int); // 6.4 MB
    int* esrc   = (int*)p;    p += (size_t)NNZ * sizeof(int);             // 3.2 MB
    int* vsrc   = (int*)p;    p += (size_t)NNZ * sizeof(int);             // 3.2 MB
    int* eoff   = (int*)p;    p += ((size_t)N_EDGES + 8) * sizeof(int);
    int* voff   = (int*)p;    p += ((size_t)N_NODES + 8) * sizeof(int);
    int* ecnt   = (int*)p;    p += 128 * sizeof(int);   // ecnt+vcnt contiguous
    int* vcnt   = (int*)p;    p += 128 * sizeof(int);

    // 0) pack W fragments; zero bucket counters (1 KB)
    pack_W<<<32, 256, 0, stream>>>(W, Wp);
    hipMemsetAsync(ecnt, 0, 256 * sizeof(int), stream);

    // 1) fused: CSR multisplit (blocks 0..195) || MFMA GEMM (blocks 196..)
    gemm_multisplit_fused<<<MS_BLOCKS + GEMM_BLOCKS, 256, 0, stream>>>(
        X, Wp, Xpb, edge_idx, node_idx, ecnt, vcnt, etmp, vtmp);

    // 2) edge-direction CSR pack (critical path only)
    build_csr_edge<<<NB, 256, 0, stream>>>(etmp, ecnt, eoff, esrc);

    // 3) fused: node-direction CSR pack (98 blocks, hidden) || edge gather
    edge_gather_fused<<<NB + EG_BLOCKS, 256, 0, stream>>>(
        Xpb, eoff, esrc, degE, Xeb, vtmp, vcnt, voff, vsrc);

    // 4) edges -> nodes (gather, fused degV + (1+eps)*Xp residual)
    node_gather<<<(N_NODES * 64 + 255) / 256, 256, 0, stream>>>(
        Xpb, Xeb, voff, vsrc, degV, eps, out);
}

// Round 14
// 210.347 us; speedup vs baseline: 1.0194x; 1.0194x over previous
//
#include <hip/hip_runtime.h>

#define N_NODES 100000
#define N_EDGES 50000
#define NNZ     800000
#define D       256

#define BM 64            // gemm rows per block
#define GEMM_BLOCKS ((N_NODES + BM - 1) / BM)   // 1563

// bucket-sort CSR build (fixed-base gapped buckets, CAP >> max count)
#define NB   98          // buckets per direction
#define ESH  9           // edge bucket shift: 512 keys/bucket
#define VSH  10          // node bucket shift: 1024 keys/bucket
#define CAP  16384       // per-bucket capacity (mean ~8.2k, 5-sigma ~8.7k)
#define ENT  4096        // entries per multisplit block
#define MS_BLOCKS ((NNZ + ENT - 1) / ENT)   // 196

typedef __bf16 bf16x8 __attribute__((ext_vector_type(8)));
typedef float  f32x4  __attribute__((ext_vector_type(4)));
typedef unsigned int u32x4 __attribute__((ext_vector_type(4)));

// accumulate 8 bf16 (packed in u32x4) into 8 f32 accumulators
__device__ __forceinline__ void acc8(float* a, const u32x4 u) {
    union { unsigned int i; float f; } t;
    t.i = u.x << 16;         a[0] += t.f;
    t.i = u.x & 0xffff0000u; a[1] += t.f;
    t.i = u.y << 16;         a[2] += t.f;
    t.i = u.y & 0xffff0000u; a[3] += t.f;
    t.i = u.z << 16;         a[4] += t.f;
    t.i = u.z & 0xffff0000u; a[5] += t.f;
    t.i = u.w << 16;         a[6] += t.f;
    t.i = u.w & 0xffff0000u; a[7] += t.f;
}

__device__ __forceinline__ void unpack8(float* a, const u32x4 u) {
    union { unsigned int i; float f; } t;
    t.i = u.x << 16;         a[0] = t.f;
    t.i = u.x & 0xffff0000u; a[1] = t.f;
    t.i = u.y << 16;         a[2] = t.f;
    t.i = u.y & 0xffff0000u; a[3] = t.f;
    t.i = u.z << 16;         a[4] = t.f;
    t.i = u.z & 0xffff0000u; a[5] = t.f;
    t.i = u.w << 16;         a[6] = t.f;
    t.i = u.w & 0xffff0000u; a[7] = t.f;
}

// ---------------------------------------------------------------------------
// Kernel 0: pack W (f32 [256][256]) into bf16 MFMA b-fragment order.
// ---------------------------------------------------------------------------
__global__ __launch_bounds__(256) void pack_W(const float* __restrict__ W,
                                              bf16x8* __restrict__ Wp) {
    const int t = blockIdx.x * 256 + threadIdx.x;   // 8192 total
    if (t >= 8 * 16 * 64) return;
    const int ks  = t >> 10;
    const int n16 = (t >> 6) & 15;
    const int l   = t & 63;
    const int kb  = ks * 32 + (l >> 4) * 8;
    const int col = n16 * 16 + (l & 15);
    bf16x8 v;
    #pragma unroll
    for (int j = 0; j < 8; ++j) v[j] = (__bf16)W[(size_t)(kb + j) * D + col];
    Wp[t] = v;
}

// ---------------------------------------------------------------------------
// Fused kernel: blocks [0, MS_BLOCKS) = multisplit (memory/atomic-bound),
// blocks [MS_BLOCKS, MS_BLOCKS+GEMM_BLOCKS) = MFMA GEMM (compute-bound).
// ---------------------------------------------------------------------------
__global__ __launch_bounds__(256) void gemm_multisplit_fused(
        const float* __restrict__ X, const bf16x8* __restrict__ Wp,
        __bf16* __restrict__ Xpb,
        const int* __restrict__ ei, const int* __restrict__ ni,
        int* __restrict__ ecnt, int* __restrict__ vcnt,
        unsigned int* __restrict__ etmp, unsigned int* __restrict__ vtmp) {
    __shared__ __align__(16) char smem[BM * D * sizeof(__bf16)];  // 32 KB
    const int tid = threadIdx.x;

    if (blockIdx.x < MS_BLOCKS) {
        // ================= multisplit =================
        int* eh = reinterpret_cast<int*>(smem);
        int* vh = eh + 128;
        int* eb = vh + 128;
        int* vb = eb + 128;
        if (tid < 128) { eh[tid] = 0; vh[tid] = 0; }
        __syncthreads();
        const int start = blockIdx.x * ENT;
        int ek[ENT / 256], nk[ENT / 256];
        #pragma unroll
        for (int k = 0; k < ENT / 256; ++k) {
            const int g = start + k * 256 + tid;
            if (g < NNZ) {
                ek[k] = __builtin_nontemporal_load(ei + g);
                nk[k] = __builtin_nontemporal_load(ni + g);
                atomicAdd(&eh[ek[k] >> ESH], 1);
                atomicAdd(&vh[nk[k] >> VSH], 1);
            } else { ek[k] = -1; nk[k] = -1; }
        }
        __syncthreads();
        if (tid < NB) {
            eb[tid] = eh[tid] ? (tid * CAP + atomicAdd(&ecnt[tid], eh[tid])) : 0;
            vb[tid] = vh[tid] ? (tid * CAP + atomicAdd(&vcnt[tid], vh[tid])) : 0;
        }
        __syncthreads();
        if (tid < 128) { eh[tid] = 0; vh[tid] = 0; }
        __syncthreads();
        #pragma unroll
        for (int k = 0; k < ENT / 256; ++k) {
            if (ek[k] >= 0) {
                int b = ek[k] >> ESH;
                int r = atomicAdd(&eh[b], 1);
                etmp[eb[b] + r] = ((unsigned)(ek[k] & ((1 << ESH) - 1)) << 17) | (unsigned)nk[k];
                b = nk[k] >> VSH;
                r = atomicAdd(&vh[b], 1);
                vtmp[vb[b] + r] = ((unsigned)(nk[k] & ((1 << VSH) - 1)) << 16) | (unsigned)ek[k];
            }
        }
        return;
    }

    // ================= GEMM =================
    __bf16 (*As)[D] = reinterpret_cast<__bf16 (*)[D]>(smem);
    const int r0 = (blockIdx.x - MS_BLOCKS) * BM;

    #pragma unroll
    for (int i = 0; i < 8; ++i) {
        const int g   = tid + i * 256;
        const int row = g >> 5;
        const int cc  = g & 31;
        const int gr  = min(r0 + row, N_NODES - 1);
        const float4 f0 = reinterpret_cast<const float4*>(X)[(size_t)gr * 64 + cc * 2 + 0];
        const float4 f1 = reinterpret_cast<const float4*>(X)[(size_t)gr * 64 + cc * 2 + 1];
        bf16x8 v;
        v[0] = (__bf16)f0.x; v[1] = (__bf16)f0.y; v[2] = (__bf16)f0.z; v[3] = (__bf16)f0.w;
        v[4] = (__bf16)f1.x; v[5] = (__bf16)f1.y; v[6] = (__bf16)f1.z; v[7] = (__bf16)f1.w;
        const int sw = cc ^ (row & 7);
        *reinterpret_cast<bf16x8*>(&As[row][sw * 8]) = v;
    }
    __syncthreads();

    const int w = tid >> 6;
    const int l = tid & 63;

    f32x4 acc[4][4];
    #pragma unroll
    for (int mt = 0; mt < 4; ++mt)
        #pragma unroll
        for (int nt = 0; nt < 4; ++nt) acc[mt][nt] = (f32x4){0.f, 0.f, 0.f, 0.f};

    #pragma unroll
    for (int ks = 0; ks < 8; ++ks) {
        bf16x8 a[4];
        #pragma unroll
        for (int mt = 0; mt < 4; ++mt) {
            const int row = mt * 16 + (l & 15);
            const int ch  = (ks * 4 + (l >> 4)) ^ (row & 7);
            a[mt] = *reinterpret_cast<const bf16x8*>(&As[row][ch * 8]);
        }
        #pragma unroll
        for (int nt = 0; nt < 4; ++nt) {
            const bf16x8 b = Wp[(ks * 16 + w * 4 + nt) * 64 + l];
            #pragma unroll
            for (int mt = 0; mt < 4; ++mt)
                acc[mt][nt] = __builtin_amdgcn_mfma_f32_16x16x32_bf16(a[mt], b, acc[mt][nt], 0, 0, 0);
        }
    }

    #pragma unroll
    for (int mt = 0; mt < 4; ++mt) {
        const int rbase = r0 + mt * 16 + (l >> 4) * 4;
        #pragma unroll
        for (int reg = 0; reg < 4; ++reg) {
            const int r = rbase + reg;
            if (r >= N_NODES) continue;
            #pragma unroll
            for (int nt = 0; nt < 4; ++nt)
                Xpb[(size_t)r * D + w * 64 + nt * 16 + (l & 15)] = (__bf16)acc[mt][nt][reg];
        }
    }
}

// ---------------------------------------------------------------------------
// build_csr with folded bucket scan: each block re-derives the 98-bucket
// exclusive prefix from the count array, then per-key count + LDS scan ->
// CSR offsets, then ranks gapped tmp entries into packed src.
// ---------------------------------------------------------------------------
__global__ __launch_bounds__(256) void build_csr(const unsigned int* __restrict__ etmp,
                                                 const unsigned int* __restrict__ vtmp,
                                                 const int* __restrict__ ecnt,
                                                 const int* __restrict__ vcnt,
                                                 int* __restrict__ eoff,
                                                 int* __restrict__ voff,
                                                 int* __restrict__ esrc,
                                                 int* __restrict__ vsrc) {
    __shared__ int cnt[1024];
    __shared__ int s[256];
    const bool is_e = blockIdx.x < NB;
    const int b = is_e ? blockIdx.x : blockIdx.x - NB;
    const unsigned int* tmp = is_e ? etmp : vtmp;
    const int* gc = is_e ? ecnt : vcnt;
    int* off = is_e ? eoff : voff;
    int* src = is_e ? esrc : vsrc;
    const int sh    = is_e ? ESH : VSH;
    const int ksh   = is_e ? 17 : 16;                 // payload bits
    const unsigned pmask = (1u << ksh) - 1u;
    const int klo   = b << sh;
    const int nkeys = is_e ? N_EDGES : N_NODES;
    const int nk    = min(1 << sh, nkeys - klo);
    const int t = threadIdx.x;

    // fold: bucket-count scan (98 values) to derive packed base
    int c = (t < NB) ? gc[t] : 0;
    s[t] = c; __syncthreads();
    #pragma unroll
    for (int d = 1; d < 256; d <<= 1) { int x = (t >= d) ? s[t - d] : 0; __syncthreads(); s[t] += x; __syncthreads(); }
    const int base_out = s[b] - gc[b];     // exclusive prefix at b
    const int count    = gc[b];
    const int base_in  = b * CAP;
    __syncthreads();

    if (t == 0 && b == 0) off[nkeys] = NNZ;   // CSR sentinel

    #pragma unroll
    for (int q = 0; q < 4; ++q) cnt[t * 4 + q] = 0;
    __syncthreads();
    for (int i = t; i < count; i += 256)
        atomicAdd(&cnt[tmp[base_in + i] >> ksh], 1);
    __syncthreads();
    int v[4]; int ts = 0;
    #pragma unroll
    for (int q = 0; q < 4; ++q) { v[q] = cnt[t * 4 + q]; ts += v[q]; }
    s[t] = ts; __syncthreads();
    #pragma unroll
    for (int d = 1; d < 256; d <<= 1) { int x = (t >= d) ? s[t - d] : 0; __syncthreads(); s[t] += x; __syncthreads(); }
    int run = s[t] - ts;
    #pragma unroll
    for (int q = 0; q < 4; ++q) { cnt[t * 4 + q] = run; run += v[q]; }
    __syncthreads();
    #pragma unroll
    for (int q = 0; q < 4; ++q) {
        const int j = t * 4 + q;
        if (j < nk) off[klo + j] = base_out + cnt[j];
    }
    __syncthreads();
    for (int i = t; i < count; i += 256) {
        const unsigned int pr = tmp[base_in + i];
        const int p = atomicAdd(&cnt[pr >> ksh], 1);
        src[base_out + p] = (int)(pr & pmask);
    }
}

// ---------------------------------------------------------------------------
// Stage 1: Xe[e] = degE[e] * sum_{j in edge e} Xp[esrc[j]]
// ---------------------------------------------------------------------------
__global__ __launch_bounds__(256) void edge_gather(
        const __bf16* __restrict__ Xpb, const int* __restrict__ eoff,
        const int* __restrict__ esrc, const float* __restrict__ degE,
        __bf16* __restrict__ Xeb) {
    const int e = (blockIdx.x * 256 + threadIdx.x) >> 6;
    if (e >= N_EDGES) return;
    const int lane = threadIdx.x & 63;
    const int half = lane >> 5;
    const int c0   = (lane & 31) * 8;
    const int beg = eoff[e], end = eoff[e + 1];
    const unsigned short* Xu = reinterpret_cast<const unsigned short*>(Xpb);

    float acc[8];
    #pragma unroll
    for (int q = 0; q < 8; ++q) acc[q] = 0.f;

    for (int cb = beg; cb < end; cb += 64) {
        const int cnt = min(64, end - cb);
        const int my = (lane < cnt) ? __builtin_nontemporal_load(esrc + cb + lane) : 0;
        int jj = 0;
        for (; jj + 8 <= cnt; jj += 8) {
            const int r0 = __shfl(my, jj + half);
            const int r1 = __shfl(my, jj + 2 + half);
            const int r2 = __shfl(my, jj + 4 + half);
            const int r3 = __shfl(my, jj + 6 + half);
            const u32x4 u0 = *reinterpret_cast<const u32x4*>(Xu + (size_t)r0 * D + c0);
            const u32x4 u1 = *reinterpret_cast<const u32x4*>(Xu + (size_t)r1 * D + c0);
            const u32x4 u2 = *reinterpret_cast<const u32x4*>(Xu + (size_t)r2 * D + c0);
            const u32x4 u3 = *reinterpret_cast<const u32x4*>(Xu + (size_t)r3 * D + c0);
            acc8(acc, u0); acc8(acc, u1); acc8(acc, u2); acc8(acc, u3);
        }
        for (; jj + 4 <= cnt; jj += 4) {
            const int r0 = __shfl(my, jj + half);
            const int r1 = __shfl(my, jj + 2 + half);
            const u32x4 u0 = *reinterpret_cast<const u32x4*>(Xu + (size_t)r0 * D + c0);
            const u32x4 u1 = *reinterpret_cast<const u32x4*>(Xu + (size_t)r1 * D + c0);
            acc8(acc, u0); acc8(acc, u1);
        }
        for (; jj < cnt; jj += 2) {
            const int rr = jj + half;
            const int r = __shfl(my, rr < cnt ? rr : cnt - 1);
            if (rr < cnt) {
                const u32x4 u = *reinterpret_cast<const u32x4*>(Xu + (size_t)r * D + c0);
                acc8(acc, u);
            }
        }
    }

    #pragma unroll
    for (int q = 0; q < 8; ++q) acc[q] += __shfl_xor(acc[q], 32);

    if (half == 0) {
        const float sc = degE[e];
        bf16x8 v;
        #pragma unroll
        for (int q = 0; q < 8; ++q) v[q] = (__bf16)(acc[q] * sc);
        __builtin_nontemporal_store(v, reinterpret_cast<bf16x8*>(
            Xeb + (size_t)e * D + c0));
    }
}

// ---------------------------------------------------------------------------
// Stage 2 (fused finalize):
//   out[n] = (1+eps)*Xp[n] + degV[n] * sum_{j in node n} Xe[vsrc[j]]
// ---------------------------------------------------------------------------
__global__ __launch_bounds__(256) void node_gather(
        const __bf16* __restrict__ Xpb, const __bf16* __restrict__ Xeb,
        const int* __restrict__ voff, const int* __restrict__ vsrc,
        const float* __restrict__ degV, const float* __restrict__ eps,
        float* __restrict__ out) {
    const int nd = (blockIdx.x * 256 + threadIdx.x) >> 6;
    if (nd >= N_NODES) return;
    const int lane = threadIdx.x & 63;
    const int half = lane >> 5;
    const int c0   = (lane & 31) * 8;
    const int beg = voff[nd], end = voff[nd + 1];
    const unsigned short* Xu = reinterpret_cast<const unsigned short*>(Xeb);

    const u32x4 up = __builtin_nontemporal_load(reinterpret_cast<const u32x4*>(
        reinterpret_cast<const unsigned short*>(Xpb) + (size_t)nd * D + c0));

    float acc[8];
    #pragma unroll
    for (int q = 0; q < 8; ++q) acc[q] = 0.f;

    for (int cb = beg; cb < end; cb += 64) {
        const int cnt = min(64, end - cb);
        const int my = (lane < cnt) ? __builtin_nontemporal_load(vsrc + cb + lane) : 0;
        int jj = 0;
        for (; jj + 8 <= cnt; jj += 8) {
            const int r0 = __shfl(my, jj + half);
            const int r1 = __shfl(my, jj + 2 + half);
            const int r2 = __shfl(my, jj + 4 + half);
            const int r3 = __shfl(my, jj + 6 + half);
            const u32x4 u0 = *reinterpret_cast<const u32x4*>(Xu + (size_t)r0 * D + c0);
            const u32x4 u1 = *reinterpret_cast<const u32x4*>(Xu + (size_t)r1 * D + c0);
            const u32x4 u2 = *reinterpret_cast<const u32x4*>(Xu + (size_t)r2 * D + c0);
            const u32x4 u3 = *reinterpret_cast<const u32x4*>(Xu + (size_t)r3 * D + c0);
            acc8(acc, u0); acc8(acc, u1); acc8(acc, u2); acc8(acc, u3);
        }
        for (; jj + 4 <= cnt; jj += 4) {
            const int r0 = __shfl(my, jj + half);
            const int r1 = __shfl(my, jj + 2 + half);
            const u32x4 u0 = *reinterpret_cast<const u32x4*>(Xu + (size_t)r0 * D + c0);
            const u32x4 u1 = *reinterpret_cast<const u32x4*>(Xu + (size_t)r1 * D + c0);
            acc8(acc, u0); acc8(acc, u1);
        }
        for (; jj < cnt; jj += 2) {
            const int rr = jj + half;
            const int r = __shfl(my, rr < cnt ? rr : cnt - 1);
            if (rr < cnt) {
                const u32x4 u = *reinterpret_cast<const u32x4*>(Xu + (size_t)r * D + c0);
                acc8(acc, u);
            }
        }
    }

    #pragma unroll
    for (int q = 0; q < 8; ++q) acc[q] += __shfl_xor(acc[q], 32);

    if (half == 0) {
        const float dv = degV[nd];
        const float ep = 1.f + eps[0];
        float xr[8]; unpack8(xr, up);
        f32x4 o0, o1;
        o0.x = ep * xr[0] + dv * acc[0];
        o0.y = ep * xr[1] + dv * acc[1];
        o0.z = ep * xr[2] + dv * acc[2];
        o0.w = ep * xr[3] + dv * acc[3];
        o1.x = ep * xr[4] + dv * acc[4];
        o1.y = ep * xr[5] + dv * acc[5];
        o1.z = ep * xr[6] + dv * acc[6];
        o1.w = ep * xr[7] + dv * acc[7];
        float* op = out + (size_t)nd * D + c0;
        __builtin_nontemporal_store(o0, reinterpret_cast<f32x4*>(op));
        __builtin_nontemporal_store(o1, reinterpret_cast<f32x4*>(op) + 1);
    }
}

// ---------------------------------------------------------------------------
extern "C" void kernel_launch(void* const* d_in, const int* in_sizes, int n_in,
                              void* d_out, int out_size, void* d_ws, size_t ws_size,
                              hipStream_t stream) {
    const float* X        = (const float*)d_in[0];
    const float* W        = (const float*)d_in[1];
    const float* eps      = (const float*)d_in[2];
    const float* degE     = (const float*)d_in[3];
    const float* degV     = (const float*)d_in[4];
    const int*   node_idx = (const int*)d_in[5];
    const int*   edge_idx = (const int*)d_in[6];

    float* out = (float*)d_out;

    // ---- workspace layout ----
    char* p = (char*)d_ws;
    __bf16* Xpb = (__bf16*)p; p += (size_t)N_NODES * D * sizeof(__bf16);  // 51.2 MB
    __bf16* Xeb = (__bf16*)p; p += (size_t)N_EDGES * D * sizeof(__bf16);  // 25.6 MB
    bf16x8* Wp  = (bf16x8*)p; p += (size_t)8 * 16 * 64 * sizeof(bf16x8);  // 128 KB
    unsigned int* etmp = (unsigned int*)p; p += (size_t)NB * CAP * sizeof(unsigned int); // 6.4 MB
    unsigned int* vtmp = (unsigned int*)p; p += (size_t)NB * CAP * sizeof(unsigned int); // 6.4 MB
    int* esrc   = (int*)p;    p += (size_t)NNZ * sizeof(int);             // 3.2 MB
    int* vsrc   = (int*)p;    p += (size_t)NNZ * sizeof(int);             // 3.2 MB
    int* eoff   = (int*)p;    p += ((size_t)N_EDGES + 8) * sizeof(int);
    int* voff   = (int*)p;    p += ((size_t)N_NODES + 8) * sizeof(int);
    int* ecnt   = (int*)p;    p += 128 * sizeof(int);   // ecnt+vcnt contiguous
    int* vcnt   = (int*)p;    p += 128 * sizeof(int);

    // 0) pack W fragments; zero bucket counters (1 KB)
    pack_W<<<32, 256, 0, stream>>>(W, Wp);
    hipMemsetAsync(ecnt, 0, 256 * sizeof(int), stream);

    // 1) fused: CSR multisplit (blocks 0..195) || MFMA GEMM (blocks 196..)
    gemm_multisplit_fused<<<MS_BLOCKS + GEMM_BLOCKS, 256, 0, stream>>>(
        X, Wp, Xpb, edge_idx, node_idx, ecnt, vcnt, etmp, vtmp);

    // 2) pack gapped buckets -> CSR offsets + packed src (scan folded in)
    build_csr<<<2 * NB, 256, 0, stream>>>(etmp, vtmp, ecnt, vcnt,
                                          eoff, voff, esrc, vsrc);

    // 3) nodes -> edges (gather, fused degE)
    edge_gather<<<(N_EDGES * 64 + 255) / 256, 256, 0, stream>>>(
        Xpb, eoff, esrc, degE, Xeb);

    // 4) edges -> nodes (gather, fused degV + (1+eps)*Xp residual)
    node_gather<<<(N_NODES * 64 + 255) / 256, 256, 0, stream>>>(
        Xpb, Xeb, voff, vsrc, degV, eps, out);
}